// Round 3
// baseline (232.177 us; speedup 1.0000x reference)
//
#include <hip/hip_runtime.h>

#define Bsz 512
#define Nn  128
#define Dd  256
#define Tt  512

typedef __attribute__((ext_vector_type(8))) short short8;
typedef __attribute__((ext_vector_type(4))) float f32x4;

__device__ __forceinline__ ushort f2bf(float f) {
    union { float f; unsigned u; } v; v.f = f;
    unsigned r = v.u + 0x7fffu + ((v.u >> 16) & 1u);  // RNE
    return (ushort)(r >> 16);
}
__device__ __forceinline__ unsigned pk2(float a, float b) {
    return (unsigned)f2bf(a) | ((unsigned)f2bf(b) << 16);
}

// ---------------------------------------------------------------------------
// prep1, grid (6, B):
//   role bx<2 : stream x -> lin-dot partials (dotv2) + bf16 xT[b][d][k]
//   role bx>=2: row-sum stats for 32 adj rows -> disG, maskG
// ---------------------------------------------------------------------------
__global__ __launch_bounds__(256) void prep1(
    const float* __restrict__ x, const float* __restrict__ adj,
    const float* __restrict__ lin_w,
    float* __restrict__ dotv2, ushort* __restrict__ xT,
    float* __restrict__ disG, float* __restrict__ maskG)
{
    const int bx = blockIdx.x, b = blockIdx.y;
    const int t = threadIdx.x;
    __shared__ float xbufT[32][130];
    __shared__ float pdot[128][8];
    __shared__ float wS[128];
    __shared__ float red[32][8];

    if (bx < 2) {
        const int h = bx;
        if (t < 128) wS[t] = lin_w[h * 128 + t];
        const int c4 = t & 7;
        const int kb = t >> 3;
        const int kc = t & 15, dsub = t >> 4;
        float p[4] = {0.f, 0.f, 0.f, 0.f};
        __syncthreads();
        for (int c = 0; c < 4; ++c) {
            const int dl = 4 * c4;
            float4 v[4];
#pragma unroll
            for (int i = 0; i < 4; ++i)
                v[i] = *(const float4*)&x[((size_t)b * Nn + (kb + 32 * i)) * Dd
                                          + h * 128 + c * 32 + dl];
            const float w0 = wS[c*32+dl],   w1 = wS[c*32+dl+1];
            const float w2 = wS[c*32+dl+2], w3 = wS[c*32+dl+3];
#pragma unroll
            for (int i = 0; i < 4; ++i) {
                p[i] += v[i].x*w0 + v[i].y*w1 + v[i].z*w2 + v[i].w*w3;
                xbufT[dl    ][kb + 32*i] = v[i].x;
                xbufT[dl + 1][kb + 32*i] = v[i].y;
                xbufT[dl + 2][kb + 32*i] = v[i].z;
                xbufT[dl + 3][kb + 32*i] = v[i].w;
            }
            __syncthreads();
#pragma unroll
            for (int pp = 0; pp < 2; ++pp) {
                int d = dsub + 16 * pp;
                float2 q0 = *(float2*)&xbufT[d][kc*8 + 0];
                float2 q1 = *(float2*)&xbufT[d][kc*8 + 2];
                float2 q2 = *(float2*)&xbufT[d][kc*8 + 4];
                float2 q3 = *(float2*)&xbufT[d][kc*8 + 6];
                uint4 pkv;
                pkv.x = pk2(q0.x, q0.y);
                pkv.y = pk2(q1.x, q1.y);
                pkv.z = pk2(q2.x, q2.y);
                pkv.w = pk2(q3.x, q3.y);
                *(uint4*)&xT[((size_t)b * Dd + h * 128 + c * 32 + d) * Nn + kc * 8] = pkv;
            }
            __syncthreads();
        }
#pragma unroll
        for (int i = 0; i < 4; ++i) pdot[kb + 32*i][c4] = p[i];
        __syncthreads();
        if (t < 128) {
            float s = 0.f;
#pragma unroll
            for (int j = 0; j < 8; ++j) s += pdot[t][j];
            dotv2[((size_t)b * Nn + t) * 2 + h] = s;
        }
    } else {
        const int g = bx - 2;              // 0..3
        const int r0 = g * 32;
        const int row = r0 + (t >> 3), sub = t & 7;
        const float* rp = adj + (size_t)b * Nn * Nn + (size_t)row * Nn + sub * 4;
        float4 a4 = {0.f, 0.f, 0.f, 0.f};
#pragma unroll
        for (int j = 0; j < 4; ++j) {
            float4 v = *(const float4*)(rp + j * 32);
            a4.x += v.x; a4.y += v.y; a4.z += v.z; a4.w += v.w;
        }
        red[t >> 3][sub] = (a4.x + a4.y) + (a4.z + a4.w);
        __syncthreads();
        if (t < 32) {
            float s = 0.f;
#pragma unroll
            for (int j = 0; j < 8; ++j) s += red[t][j];
            maskG[(size_t)b * Nn + r0 + t] = (s > 0.f) ? 1.f : 0.f;
            disG[(size_t)b * Nn + r0 + t]  = 1.f / sqrtf(fmaxf(s + 1.f, 1.f));
        }
    }
}

// ---------------------------------------------------------------------------
// alphacut: per-batch chain (tt -> matvec -> alpha -> cut -> u -> matvec ->
// rowc). adj read straight from global (L2/L3 hot). Tiny LDS.
// ---------------------------------------------------------------------------
__global__ __launch_bounds__(256) void alphacut(
    const float* __restrict__ adj, const int* __restrict__ head,
    const float* __restrict__ dotv2, const float* __restrict__ disG,
    const float* __restrict__ maskG, const float* __restrict__ bias,
    float* __restrict__ uG, float* __restrict__ rowcG)
{
    const int b = blockIdx.x, t = threadIdx.x;
    __shared__ float ttS[128], disS[128], maskS[128], alphaS[128], uS[128];
    __shared__ float partS[128][2];
    __shared__ int   flags[128];
    __shared__ int   nuniq;
    __shared__ float cutS;
    const float bias0 = bias[0];

    if (t < 128) flags[t] = 0;
    if (t == 0) { nuniq = 0; cutS = 0.f; }
    __syncthreads();
    { int h0 = head[(size_t)b * Tt + t];
      int h1 = head[(size_t)b * Tt + 256 + t];
      flags[h0] = 1; flags[h1] = 1; }
    if (t < 128) {
        float d = disG[(size_t)b * Nn + t];
        disS[t] = d; maskS[t] = maskG[(size_t)b * Nn + t];
        ttS[t] = d * (dotv2[((size_t)b * Nn + t) * 2]
                    + dotv2[((size_t)b * Nn + t) * 2 + 1]);
    }
    __syncthreads();
    if (t < 128) atomicAdd(&nuniq, flags[t]);

    const float* adjb = adj + (size_t)b * Nn * Nn;
    const int r = t >> 1, hh = t & 1, cb = hh * 64;
    { // matvec adj * tt
        float4 a = {0.f, 0.f, 0.f, 0.f};
#pragma unroll
        for (int j = 0; j < 16; ++j) {
            float4 v = *(const float4*)&adjb[(size_t)r * Nn + cb + 4*j];
            float4 w = *(float4*)&ttS[cb + 4*j];
            a.x += v.x*w.x; a.y += v.y*w.y; a.z += v.z*w.z; a.w += v.w*w.w;
        }
        partS[r][hh] = (a.x + a.y) + (a.z + a.w);
    }
    __syncthreads();
    if (t < 128) {
        float mv = partS[t][0] + partS[t][1];
        float o  = maskS[t] * disS[t] * (mv + ttS[t]) + bias0;
        alphaS[t] = 1.f / (1.f + expf(-o * o));
    }
    __syncthreads();
    if (t < 128) {  // exact k-th largest (rank select, ties == sort)
        int nu = nuniq;
        if (nu > 1) {
            int idx = (int)ceilf((float)nu * 0.1f);
            if (idx > Nn - 1) idx = Nn - 1;
            float an = alphaS[t];
            int cg = 0, ce = 0;
            for (int j = 0; j < Nn; ++j) {
                float aj = alphaS[j];
                cg += (aj > an); ce += (aj == an);
            }
            if (cg <= idx && idx < cg + ce) cutS = an;  // benign same-value race
        }
    }
    __syncthreads();
    if (t < 128) uS[t] = fmaxf(alphaS[t] + 1e-7f - cutS, 0.f) * disS[t];
    __syncthreads();
    { // matvec adj * u
        float4 a = {0.f, 0.f, 0.f, 0.f};
#pragma unroll
        for (int j = 0; j < 16; ++j) {
            float4 v = *(const float4*)&adjb[(size_t)r * Nn + cb + 4*j];
            float4 w = *(float4*)&uS[cb + 4*j];
            a.x += v.x*w.x; a.y += v.y*w.y; a.z += v.z*w.z; a.w += v.w*w.w;
        }
        partS[r][hh] = (a.x + a.y) + (a.z + a.w);
    }
    __syncthreads();
    if (t < 128) {
        float tot  = partS[t][0] + partS[t][1] + uS[t];
        float rsum = maskS[t] * disS[t] * tot;
        rowcG[(size_t)b * Nn + t] = maskS[t] * disS[t] / fmaxf(rsum, 1e-12f);
        uG[(size_t)b * Nn + t]    = uS[t];
    }
}

// ---------------------------------------------------------------------------
// build_st, grid (4, B): slab-transpose 32 adj columns via LDS, emit
// ST[b][m][k] = rowc_k * (adj[k][m] + delta) * u_m in bf16, coalesced.
// ---------------------------------------------------------------------------
__global__ __launch_bounds__(256) void build_st(
    const float* __restrict__ adj, const float* __restrict__ uG,
    const float* __restrict__ rowcG, ushort* __restrict__ STbf)
{
    const int g = blockIdx.x, b = blockIdx.y, t = threadIdx.x;
    const int m0 = g * 32;
    __shared__ float slabT[32][132];
    __shared__ float rowcS[128];
    __shared__ float uS[32];

    if (t < 128) rowcS[t] = rowcG[(size_t)b * Nn + t];
    if (t < 32)  uS[t]    = uG[(size_t)b * Nn + m0 + t];

    const float* adjb = adj + (size_t)b * Nn * Nn;
#pragma unroll
    for (int i = 0; i < 4; ++i) {
        int f = t + 256 * i;               // float4 id over 128x32 slab
        int k = f >> 3, cc = (f & 7) * 4;
        float4 v = *(const float4*)&adjb[(size_t)k * Nn + m0 + cc];
        slabT[cc    ][k] = v.x; slabT[cc + 1][k] = v.y;
        slabT[cc + 2][k] = v.z; slabT[cc + 3][k] = v.w;
    }
    __syncthreads();

    const int mloc = t >> 3, m = m0 + mloc;
    const int ks   = (t & 7) * 16;
    const float um = uS[mloc];
    float vv[16];
#pragma unroll
    for (int q = 0; q < 4; ++q) {
        float4 a = *(float4*)&slabT[mloc][ks + 4 * q];
        int k = ks + 4 * q;
        vv[4*q    ] = rowcS[k    ] * (a.x + ((k     == m) ? 1.f : 0.f)) * um;
        vv[4*q + 1] = rowcS[k + 1] * (a.y + ((k + 1 == m) ? 1.f : 0.f)) * um;
        vv[4*q + 2] = rowcS[k + 2] * (a.z + ((k + 2 == m) ? 1.f : 0.f)) * um;
        vv[4*q + 3] = rowcS[k + 3] * (a.w + ((k + 3 == m) ? 1.f : 0.f)) * um;
    }
    uint4 p0, p1;
    p0.x = pk2(vv[0],  vv[1]);  p0.y = pk2(vv[2],  vv[3]);
    p0.z = pk2(vv[4],  vv[5]);  p0.w = pk2(vv[6],  vv[7]);
    p1.x = pk2(vv[8],  vv[9]);  p1.y = pk2(vv[10], vv[11]);
    p1.z = pk2(vv[12], vv[13]); p1.w = pk2(vv[14], vv[15]);
    ushort* outp = STbf + ((size_t)b * Nn + m) * Nn + ks;
    *(uint4*)outp       = p0;
    *(uint4*)(outp + 8) = p1;
}

// ---------------------------------------------------------------------------
// gemm3, grid (3, B): role 0/1 = emb halves (S^T x), role 2 = fused
// new_adj = S^T (A S) with P^T kept in LDS.
// ---------------------------------------------------------------------------
__global__ __launch_bounds__(256, 2) void gemm3(
    const float* __restrict__ adj, const ushort* __restrict__ STbf,
    const ushort* __restrict__ xT, float* __restrict__ emb,
    float* __restrict__ nadj)
{
    const int role = blockIdx.x, b = blockIdx.y;
    __shared__ ushort bufB[128][136];
    __shared__ ushort bufS[128][136];
    const int t = threadIdx.x;

    const uint4* sg = (const uint4*)(STbf + (size_t)b * Nn * Nn);
#pragma unroll
    for (int i = 0; i < 8; ++i) {
        int f = t + 256 * i;
        *(uint4*)&bufS[f >> 4][(f & 15) * 8] = sg[f];
    }
    if (role < 2) {
        const uint4* xg = (const uint4*)(xT + ((size_t)b * Dd + role * 128) * Nn);
#pragma unroll
        for (int i = 0; i < 8; ++i) {
            int f = t + 256 * i;
            *(uint4*)&bufB[f >> 4][(f & 15) * 8] = xg[f];
        }
    } else {
        const float* adjb = adj + (size_t)b * Nn * Nn;
#pragma unroll
        for (int i = 0; i < 16; ++i) {
            int f = t + 256 * i;
            int rr = f >> 5, c4 = f & 31;
            float4 v = *(const float4*)&adjb[(size_t)rr * Nn + c4 * 4];
            uint2 w; w.x = pk2(v.x, v.y); w.y = pk2(v.z, v.w);
            *(uint2*)&bufB[rr][c4 * 4] = w;
        }
    }
    __syncthreads();

    const int lane = t & 63, wv = t >> 6;
    const int l15 = lane & 15, quad = lane >> 4;
    const int m0 = wv * 32;
    f32x4 acc[2][8];
#pragma unroll
    for (int mt = 0; mt < 2; ++mt)
#pragma unroll
        for (int nt = 0; nt < 8; ++nt) acc[mt][nt] = (f32x4){0.f, 0.f, 0.f, 0.f};

    if (role < 2) {
        // emb = S^T x : A = bufS, B = bufB
#pragma unroll
        for (int k0 = 0; k0 < 128; k0 += 32) {
            short8 a0 = *(const short8*)&bufS[m0 + l15][k0 + quad * 8];
            short8 a1 = *(const short8*)&bufS[m0 + 16 + l15][k0 + quad * 8];
            short8 bf[8];
#pragma unroll
            for (int nt = 0; nt < 8; ++nt)
                bf[nt] = *(const short8*)&bufB[nt * 16 + l15][k0 + quad * 8];
#pragma unroll
            for (int nt = 0; nt < 8; ++nt) {
                acc[0][nt] = __builtin_amdgcn_mfma_f32_16x16x32_bf16(a0, bf[nt], acc[0][nt], 0, 0, 0);
                acc[1][nt] = __builtin_amdgcn_mfma_f32_16x16x32_bf16(a1, bf[nt], acc[1][nt], 0, 0, 0);
            }
        }
        const int d0 = role * 128;
#pragma unroll
        for (int mt = 0; mt < 2; ++mt)
#pragma unroll
            for (int nt = 0; nt < 8; ++nt)
#pragma unroll
                for (int rr = 0; rr < 4; ++rr) {
                    int row = m0 + mt * 16 + quad * 4 + rr;
                    int col = d0 + nt * 16 + l15;
                    emb[((size_t)b * Nn + row) * Dd + col] = acc[mt][nt][rr];
                }
    } else {
        // G2: P = adj * S : A = bufB(adj), B = bufS
#pragma unroll
        for (int k0 = 0; k0 < 128; k0 += 32) {
            short8 a0 = *(const short8*)&bufB[m0 + l15][k0 + quad * 8];
            short8 a1 = *(const short8*)&bufB[m0 + 16 + l15][k0 + quad * 8];
            short8 bf[8];
#pragma unroll
            for (int nt = 0; nt < 8; ++nt)
                bf[nt] = *(const short8*)&bufS[nt * 16 + l15][k0 + quad * 8];
#pragma unroll
            for (int nt = 0; nt < 8; ++nt) {
                acc[0][nt] = __builtin_amdgcn_mfma_f32_16x16x32_bf16(a0, bf[nt], acc[0][nt], 0, 0, 0);
                acc[1][nt] = __builtin_amdgcn_mfma_f32_16x16x32_bf16(a1, bf[nt], acc[1][nt], 0, 0, 0);
            }
        }
        __syncthreads();
        // write P^T into bufB
#pragma unroll
        for (int mt = 0; mt < 2; ++mt)
#pragma unroll
            for (int nt = 0; nt < 8; ++nt) {
                int j    = nt * 16 + l15;
                int mcol = m0 + mt * 16 + quad * 4;
                uint2 w;
                w.x = pk2(acc[mt][nt][0], acc[mt][nt][1]);
                w.y = pk2(acc[mt][nt][2], acc[mt][nt][3]);
                *(uint2*)&bufB[j][mcol] = w;
            }
        __syncthreads();
#pragma unroll
        for (int mt = 0; mt < 2; ++mt)
#pragma unroll
            for (int nt = 0; nt < 8; ++nt) acc[mt][nt] = (f32x4){0.f, 0.f, 0.f, 0.f};
        // G3: nadj = S^T P : A = bufS, B = bufB(P^T)
#pragma unroll
        for (int k0 = 0; k0 < 128; k0 += 32) {
            short8 a0 = *(const short8*)&bufS[m0 + l15][k0 + quad * 8];
            short8 a1 = *(const short8*)&bufS[m0 + 16 + l15][k0 + quad * 8];
            short8 bf[8];
#pragma unroll
            for (int nt = 0; nt < 8; ++nt)
                bf[nt] = *(const short8*)&bufB[nt * 16 + l15][k0 + quad * 8];
#pragma unroll
            for (int nt = 0; nt < 8; ++nt) {
                acc[0][nt] = __builtin_amdgcn_mfma_f32_16x16x32_bf16(a0, bf[nt], acc[0][nt], 0, 0, 0);
                acc[1][nt] = __builtin_amdgcn_mfma_f32_16x16x32_bf16(a1, bf[nt], acc[1][nt], 0, 0, 0);
            }
        }
#pragma unroll
        for (int mt = 0; mt < 2; ++mt)
#pragma unroll
            for (int nt = 0; nt < 8; ++nt)
#pragma unroll
                for (int rr = 0; rr < 4; ++rr) {
                    int row = m0 + mt * 16 + quad * 4 + rr;
                    int col = nt * 16 + l15;
                    nadj[((size_t)b * Nn + row) * Nn + col] = acc[mt][nt][rr];
                }
    }
}

extern "C" void kernel_launch(void* const* d_in, const int* in_sizes, int n_in,
                              void* d_out, int out_size, void* d_ws, size_t ws_size,
                              hipStream_t stream)
{
    const float* x     = (const float*)d_in[0];
    const float* adj   = (const float*)d_in[1];
    const int*   head  = (const int*)d_in[2];
    const float* lin_w = (const float*)d_in[3];
    const float* bias  = (const float*)d_in[4];

    float* emb  = (float*)d_out;                          // [B,N,D]
    float* nadj = emb + (size_t)Bsz * Nn * Dd;            // [B,N,N]

    ushort* STbf  = (ushort*)d_ws;                        // [B,N,N] bf16 (S^T)
    ushort* xT    = STbf + (size_t)Bsz * Nn * Nn;         // [B,D,N] bf16
    float*  dotv2 = (float*)(xT + (size_t)Bsz * Dd * Nn); // [B,N,2]
    float*  disG  = dotv2 + (size_t)Bsz * Nn * 2;
    float*  maskG = disG + (size_t)Bsz * Nn;
    float*  uG    = maskG + (size_t)Bsz * Nn;
    float*  rowcG = uG + (size_t)Bsz * Nn;

    prep1<<<dim3(6, Bsz), 256, 0, stream>>>(x, adj, lin_w, dotv2, xT, disG, maskG);
    alphacut<<<Bsz, 256, 0, stream>>>(adj, head, dotv2, disG, maskG, bias, uG, rowcG);
    build_st<<<dim3(4, Bsz), 256, 0, stream>>>(adj, uG, rowcG, STbf);
    gemm3<<<dim3(3, Bsz), 256, 0, stream>>>(adj, STbf, xT, emb, nadj);
}

// Round 4
// 217.447 us; speedup vs baseline: 1.0677x; 1.0677x over previous
//
#include <hip/hip_runtime.h>

#define Bsz 512
#define Nn  128
#define Dd  256
#define Tt  512

typedef __attribute__((ext_vector_type(8))) short short8;
typedef __attribute__((ext_vector_type(4))) float f32x4;

__device__ __forceinline__ ushort f2bf(float f) {
    union { float f; unsigned u; } v; v.f = f;
    unsigned r = v.u + 0x7fffu + ((v.u >> 16) & 1u);  // RNE
    return (ushort)(r >> 16);
}
__device__ __forceinline__ unsigned pk2(float a, float b) {
    return (unsigned)f2bf(a) | ((unsigned)f2bf(b) << 16);
}
__device__ __forceinline__ short8 pk8(const float* v) {
    union { uint4 u; short8 s; } c;
    c.u.x = pk2(v[0], v[1]); c.u.y = pk2(v[2], v[3]);
    c.u.z = pk2(v[4], v[5]); c.u.w = pk2(v[6], v[7]);
    return c.s;
}

// One block per batch: full pipeline, no global intermediates.
__global__ __launch_bounds__(256) void mega(
    const float* __restrict__ x, const float* __restrict__ adj,
    const int* __restrict__ head, const float* __restrict__ lin_w,
    const float* __restrict__ bias,
    float* __restrict__ emb, float* __restrict__ nadj)
{
    const int b = blockIdx.x, t = threadIdx.x;
    // bufA: adj fp32 [128][132] -> later P^T ushort[128][136] -> x-quarter f32 [64][132]
    __shared__ __align__(16) float bufA[Nn][132];            // 67584 B
    __shared__ __align__(16) ushort STl[Nn][136];            // 34816 B
    __shared__ float wS[Dd];
    __shared__ float ttS[Nn], disS[Nn], maskS[Nn], alphaS[Nn], uS[Nn], rowcS[Nn];
    __shared__ float partS[Nn][2];
    __shared__ float dotP[Nn][2];
    __shared__ int   flags[Nn];
    __shared__ int   nuniq;
    __shared__ float cutS;

    const float bias0 = bias[0];
    wS[t] = lin_w[t];
    if (t < Nn) flags[t] = 0;
    if (t == 0) { nuniq = 0; cutS = 0.f; }

    // ---- stage adj fp32 -> LDS (read once per batch) ----
    const float* adjb = adj + (size_t)b * Nn * Nn;
#pragma unroll
    for (int i = 0; i < 16; ++i) {
        int f = t + 256 * i;
        int rr = f >> 5, c = (f & 31) * 4;
        *(float4*)&bufA[rr][c] = *(const float4*)&adjb[(size_t)rr * Nn + c];
    }
    __syncthreads();   // adjS visible; flags init visible

    // ---- head presence (after barrier so init is visible) ----
    { int h0 = head[(size_t)b * Tt + t];
      int h1 = head[(size_t)b * Tt + 256 + t];
      flags[h0] = 1; flags[h1] = 1; }

    // ---- lin(x) dot: 2 threads/row, 32 float4 each ----
    {
        const int dr = t >> 1, dh = t & 1;
        const float4* xr = (const float4*)(x + ((size_t)b * Nn + dr) * Dd + dh * 128);
        float p = 0.f;
#pragma unroll 8
        for (int i = 0; i < 32; ++i) {
            float4 v = xr[i];
            const float* w = &wS[dh * 128 + 4 * i];
            p += v.x * w[0] + v.y * w[1] + v.z * w[2] + v.w * w[3];
        }
        dotP[dr][dh] = p;
    }

    // ---- row sums from LDS ----
    const int r = t >> 1, hh = t & 1, cb = hh * 64;
    {
        float4 s4 = {0.f, 0.f, 0.f, 0.f};
#pragma unroll
        for (int j = 0; j < 16; ++j) {
            float4 v = *(float4*)&bufA[r][cb + 4 * j];
            s4.x += v.x; s4.y += v.y; s4.z += v.z; s4.w += v.w;
        }
        partS[r][hh] = (s4.x + s4.y) + (s4.z + s4.w);
    }
    __syncthreads();

    if (t < Nn) {
        float rs  = partS[t][0] + partS[t][1];
        maskS[t]  = (rs > 0.f) ? 1.f : 0.f;
        float dis = 1.f / sqrtf(fmaxf(rs + 1.f, 1.f));
        disS[t]   = dis;
        ttS[t]    = dis * (dotP[t][0] + dotP[t][1]);
        atomicAdd(&nuniq, flags[t]);
    }
    __syncthreads();

    { // matvec adj * tt
        float4 a = {0.f, 0.f, 0.f, 0.f};
#pragma unroll
        for (int j = 0; j < 16; ++j) {
            float4 v = *(float4*)&bufA[r][cb + 4 * j];
            float4 w = *(float4*)&ttS[cb + 4 * j];
            a.x += v.x * w.x; a.y += v.y * w.y; a.z += v.z * w.z; a.w += v.w * w.w;
        }
        partS[r][hh] = (a.x + a.y) + (a.z + a.w);
    }
    __syncthreads();
    if (t < Nn) {
        float mv = partS[t][0] + partS[t][1];
        float o  = maskS[t] * disS[t] * (mv + ttS[t]) + bias0;
        alphaS[t] = 1.f / (1.f + expf(-o * o));
    }
    __syncthreads();
    if (t < Nn) {  // exact k-th largest (rank select; ties behave like sort)
        int nu = nuniq;
        if (nu > 1) {
            int idx = (int)ceilf((float)nu * 0.1f);
            if (idx > Nn - 1) idx = Nn - 1;
            float an = alphaS[t];
            int cg = 0, ce = 0;
            for (int j = 0; j < Nn; ++j) {
                float aj = alphaS[j];
                cg += (aj > an); ce += (aj == an);
            }
            if (cg <= idx && idx < cg + ce) cutS = an;  // benign same-value race
        }
    }
    __syncthreads();
    if (t < Nn) uS[t] = fmaxf(alphaS[t] + 1e-7f - cutS, 0.f) * disS[t];
    __syncthreads();
    { // matvec adj * u (row L1; all terms >= 0)
        float4 a = {0.f, 0.f, 0.f, 0.f};
#pragma unroll
        for (int j = 0; j < 16; ++j) {
            float4 v = *(float4*)&bufA[r][cb + 4 * j];
            float4 w = *(float4*)&uS[cb + 4 * j];
            a.x += v.x * w.x; a.y += v.y * w.y; a.z += v.z * w.z; a.w += v.w * w.w;
        }
        partS[r][hh] = (a.x + a.y) + (a.z + a.w);
    }
    __syncthreads();
    if (t < Nn) {
        float tot  = partS[t][0] + partS[t][1] + uS[t];
        float rsum = maskS[t] * disS[t] * tot;
        rowcS[t]   = maskS[t] * disS[t] / fmaxf(rsum, 1e-12f);
    }
    __syncthreads();

    // ---- build ST[m][k] = rowc_k*(adj[k][m]+delta)*u_m  (bf16, in LDS) ----
    {
        const int m = r;                 // t>>1
        const float um = uS[m];
#pragma unroll
        for (int kc = 0; kc < 8; ++kc) {
            int k0 = cb + kc * 8;
            float vv[8];
#pragma unroll
            for (int j = 0; j < 8; ++j) {
                int k = k0 + j;
                vv[j] = rowcS[k] * (bufA[k][m] + ((k == m) ? 1.f : 0.f)) * um;
            }
            uint4 pkv;
            pkv.x = pk2(vv[0], vv[1]); pkv.y = pk2(vv[2], vv[3]);
            pkv.z = pk2(vv[4], vv[5]); pkv.w = pk2(vv[6], vv[7]);
            *(uint4*)&STl[m][k0] = pkv;
        }
    }
    __syncthreads();

    const int lane = t & 63, wv = t >> 6;
    const int l15 = lane & 15, quad = lane >> 4;
    const int m0 = wv * 32;
    f32x4 acc[2][8];
#pragma unroll
    for (int mt = 0; mt < 2; ++mt)
#pragma unroll
        for (int nt = 0; nt < 8; ++nt) acc[mt][nt] = (f32x4){0.f, 0.f, 0.f, 0.f};

    // ---- G2: P = adj * S  (A from fp32 LDS, converted in-reg) ----
#pragma unroll
    for (int k0 = 0; k0 < 128; k0 += 32) {
        float av[8];
        *(float4*)&av[0] = *(float4*)&bufA[m0 + l15][k0 + quad * 8];
        *(float4*)&av[4] = *(float4*)&bufA[m0 + l15][k0 + quad * 8 + 4];
        short8 a0 = pk8(av);
        *(float4*)&av[0] = *(float4*)&bufA[m0 + 16 + l15][k0 + quad * 8];
        *(float4*)&av[4] = *(float4*)&bufA[m0 + 16 + l15][k0 + quad * 8 + 4];
        short8 a1 = pk8(av);
        short8 bf[8];
#pragma unroll
        for (int nt = 0; nt < 8; ++nt)
            bf[nt] = *(const short8*)&STl[nt * 16 + l15][k0 + quad * 8];
#pragma unroll
        for (int nt = 0; nt < 8; ++nt) {
            acc[0][nt] = __builtin_amdgcn_mfma_f32_16x16x32_bf16(a0, bf[nt], acc[0][nt], 0, 0, 0);
            acc[1][nt] = __builtin_amdgcn_mfma_f32_16x16x32_bf16(a1, bf[nt], acc[1][nt], 0, 0, 0);
        }
    }
    __syncthreads();   // adj fp32 dead

    // ---- write P^T (bf16) into bufA region ----
    ushort (*PT)[136] = (ushort(*)[136])&bufA[0][0];
#pragma unroll
    for (int mt = 0; mt < 2; ++mt)
#pragma unroll
        for (int nt = 0; nt < 8; ++nt) {
            int j    = nt * 16 + l15;
            int mcol = m0 + mt * 16 + quad * 4;
            uint2 w;
            w.x = pk2(acc[mt][nt][0], acc[mt][nt][1]);
            w.y = pk2(acc[mt][nt][2], acc[mt][nt][3]);
            *(uint2*)&PT[j][mcol] = w;
        }
    __syncthreads();

#pragma unroll
    for (int mt = 0; mt < 2; ++mt)
#pragma unroll
        for (int nt = 0; nt < 8; ++nt) acc[mt][nt] = (f32x4){0.f, 0.f, 0.f, 0.f};

    // ---- G3: nadj = S^T P ----
#pragma unroll
    for (int k0 = 0; k0 < 128; k0 += 32) {
        short8 a0 = *(const short8*)&STl[m0 + l15][k0 + quad * 8];
        short8 a1 = *(const short8*)&STl[m0 + 16 + l15][k0 + quad * 8];
        short8 bf[8];
#pragma unroll
        for (int nt = 0; nt < 8; ++nt)
            bf[nt] = *(const short8*)&PT[nt * 16 + l15][k0 + quad * 8];
#pragma unroll
        for (int nt = 0; nt < 8; ++nt) {
            acc[0][nt] = __builtin_amdgcn_mfma_f32_16x16x32_bf16(a0, bf[nt], acc[0][nt], 0, 0, 0);
            acc[1][nt] = __builtin_amdgcn_mfma_f32_16x16x32_bf16(a1, bf[nt], acc[1][nt], 0, 0, 0);
        }
    }
#pragma unroll
    for (int mt = 0; mt < 2; ++mt)
#pragma unroll
        for (int nt = 0; nt < 8; ++nt)
#pragma unroll
            for (int rr = 0; rr < 4; ++rr) {
                int row = m0 + mt * 16 + quad * 4 + rr;
                int col = nt * 16 + l15;
                nadj[((size_t)b * Nn + row) * Nn + col] = acc[mt][nt][rr];
            }
    __syncthreads();   // PT dead

    // ---- emb = S^T x, d in quarters of 64; x transposed via LDS ----
    float (*xbufF)[132] = (float(*)[132])&bufA[0][0];   // [64 d][132 k]
    short8 aE[2][4];
#pragma unroll
    for (int ks = 0; ks < 4; ++ks) {
        aE[0][ks] = *(const short8*)&STl[m0 + l15][ks * 32 + quad * 8];
        aE[1][ks] = *(const short8*)&STl[m0 + 16 + l15][ks * 32 + quad * 8];
    }
    for (int qd = 0; qd < 4; ++qd) {
        const int d0 = qd * 64;
#pragma unroll
        for (int i = 0; i < 8; ++i) {
            int f = t + 256 * i;          // float4 id over 128k x 16(d4)
            int k = f >> 4, c4 = (f & 15) * 4;
            float4 v = *(const float4*)&x[((size_t)b * Nn + k) * Dd + d0 + c4];
            xbufF[c4    ][k] = v.x; xbufF[c4 + 1][k] = v.y;
            xbufF[c4 + 2][k] = v.z; xbufF[c4 + 3][k] = v.w;
        }
        __syncthreads();
        f32x4 accE[2][4];
#pragma unroll
        for (int mt = 0; mt < 2; ++mt)
#pragma unroll
            for (int nt = 0; nt < 4; ++nt) accE[mt][nt] = (f32x4){0.f, 0.f, 0.f, 0.f};
#pragma unroll
        for (int ks = 0; ks < 4; ++ks) {
            short8 bf[4];
#pragma unroll
            for (int nt = 0; nt < 4; ++nt) {
                float bv[8];
                *(float4*)&bv[0] = *(float4*)&xbufF[nt * 16 + l15][ks * 32 + quad * 8];
                *(float4*)&bv[4] = *(float4*)&xbufF[nt * 16 + l15][ks * 32 + quad * 8 + 4];
                bf[nt] = pk8(bv);
            }
#pragma unroll
            for (int nt = 0; nt < 4; ++nt) {
                accE[0][nt] = __builtin_amdgcn_mfma_f32_16x16x32_bf16(aE[0][ks], bf[nt], accE[0][nt], 0, 0, 0);
                accE[1][nt] = __builtin_amdgcn_mfma_f32_16x16x32_bf16(aE[1][ks], bf[nt], accE[1][nt], 0, 0, 0);
            }
        }
#pragma unroll
        for (int mt = 0; mt < 2; ++mt)
#pragma unroll
            for (int nt = 0; nt < 4; ++nt)
#pragma unroll
                for (int rr = 0; rr < 4; ++rr) {
                    int row = m0 + mt * 16 + quad * 4 + rr;
                    int col = d0 + nt * 16 + l15;
                    emb[((size_t)b * Nn + row) * Dd + col] = accE[mt][nt][rr];
                }
        __syncthreads();
    }
}

extern "C" void kernel_launch(void* const* d_in, const int* in_sizes, int n_in,
                              void* d_out, int out_size, void* d_ws, size_t ws_size,
                              hipStream_t stream)
{
    const float* x     = (const float*)d_in[0];
    const float* adj   = (const float*)d_in[1];
    const int*   head  = (const int*)d_in[2];
    const float* lin_w = (const float*)d_in[3];
    const float* bias  = (const float*)d_in[4];

    float* emb  = (float*)d_out;                 // [B,N,D]
    float* nadj = emb + (size_t)Bsz * Nn * Dd;   // [B,N,N]

    mega<<<Bsz, 256, 0, stream>>>(x, adj, head, lin_w, bias, emb, nadj);
}

// Round 5
// 214.449 us; speedup vs baseline: 1.0827x; 1.0140x over previous
//
#include <hip/hip_runtime.h>

#define Bsz 512
#define Nn  128
#define Dd  256
#define Tt  512

typedef __attribute__((ext_vector_type(8))) short short8;
typedef __attribute__((ext_vector_type(4))) float f32x4;

__device__ __forceinline__ ushort f2bf(float f) {
    union { float f; unsigned u; } v; v.f = f;
    unsigned r = v.u + 0x7fffu + ((v.u >> 16) & 1u);  // RNE
    return (ushort)(r >> 16);
}
__device__ __forceinline__ unsigned pk2(float a, float b) {
    return (unsigned)f2bf(a) | ((unsigned)f2bf(b) << 16);
}
__device__ __forceinline__ short8 pk8(const float* v) {
    union { uint4 u; short8 s; } c;
    c.u.x = pk2(v[0], v[1]); c.u.y = pk2(v[2], v[3]);
    c.u.z = pk2(v[4], v[5]); c.u.w = pk2(v[6], v[7]);
    return c.s;
}

// One block per batch, 1024 threads (16 waves): full pipeline, no global
// intermediates. LDS ~115 KB -> 1 block/CU but 16 waves of latency hiding.
__global__ __launch_bounds__(1024) void mega(
    const float* __restrict__ x, const float* __restrict__ adj,
    const int* __restrict__ head, const float* __restrict__ lin_w,
    const float* __restrict__ bias,
    float* __restrict__ emb, float* __restrict__ nadj)
{
    const int b = blockIdx.x, t = threadIdx.x;
    // bufA: adj fp32 [128][132] -> later P^T ushort[128][136] -> x fp32 [128][65]
    __shared__ __align__(16) float bufA[Nn][132];            // 67584 B
    __shared__ __align__(16) ushort STl[Nn][136];            // 34816 B
    __shared__ float wS[Dd];
    __shared__ float ttS[Nn], disS[Nn], maskS[Nn], alphaS[Nn], uS[Nn], rowcS[Nn];
    __shared__ float partS[Nn][9];   // pad 9: gcd(9,32)=1 -> conflict-free
    __shared__ float dotP[Nn][9];
    __shared__ int   flags[Nn];
    __shared__ int   nuniq;
    __shared__ float cutS;

    const float bias0 = bias[0];
    if (t < Dd) wS[t] = lin_w[t];
    if (t < Nn) flags[t] = 0;
    if (t == 0) { nuniq = 0; cutS = 0.f; }

    // ---- stage adj fp32 -> LDS (read once per batch) ----
    const float* adjb = adj + (size_t)b * Nn * Nn;
#pragma unroll
    for (int i = 0; i < 4; ++i) {
        int f = t + 1024 * i;
        int rr = f >> 5, c = (f & 31) * 4;
        *(float4*)&bufA[rr][c] = *(const float4*)&adjb[(size_t)rr * Nn + c];
    }
    __syncthreads();   // adj visible; flags init visible

    // ---- head presence ----
    if (t < Tt) { int h = head[(size_t)b * Tt + t]; flags[h] = 1; }

    // ---- lin(x) dot: 8 threads/row ----
    {
        const int dr = t >> 3, dh = t & 7;
        const float4* xr = (const float4*)(x + ((size_t)b * Nn + dr) * Dd + dh * 32);
        float p = 0.f;
#pragma unroll
        for (int i = 0; i < 8; ++i) {
            float4 v = xr[i];
            const float* w = &wS[dh * 32 + 4 * i];
            p += v.x * w[0] + v.y * w[1] + v.z * w[2] + v.w * w[3];
        }
        dotP[dr][dh] = p;
    }

    // ---- row sums: 8 threads/row ----
    const int r = t >> 3, seg = t & 7, cbs = seg * 16;
    {
        float4 s4 = {0.f, 0.f, 0.f, 0.f};
#pragma unroll
        for (int j = 0; j < 4; ++j) {
            float4 v = *(float4*)&bufA[r][cbs + 4 * j];
            s4.x += v.x; s4.y += v.y; s4.z += v.z; s4.w += v.w;
        }
        partS[r][seg] = (s4.x + s4.y) + (s4.z + s4.w);
    }
    __syncthreads();

    if (t < Nn) {
        float rs = 0.f, dt = 0.f;
#pragma unroll
        for (int j = 0; j < 8; ++j) { rs += partS[t][j]; dt += dotP[t][j]; }
        maskS[t]  = (rs > 0.f) ? 1.f : 0.f;
        float dis = 1.f / sqrtf(fmaxf(rs + 1.f, 1.f));
        disS[t]   = dis;
        ttS[t]    = dis * dt;
        atomicAdd(&nuniq, flags[t]);
    }
    __syncthreads();

    { // matvec adj * tt
        float4 a = {0.f, 0.f, 0.f, 0.f};
#pragma unroll
        for (int j = 0; j < 4; ++j) {
            float4 v = *(float4*)&bufA[r][cbs + 4 * j];
            float4 w = *(float4*)&ttS[cbs + 4 * j];
            a.x += v.x * w.x; a.y += v.y * w.y; a.z += v.z * w.z; a.w += v.w * w.w;
        }
        partS[r][seg] = (a.x + a.y) + (a.z + a.w);
    }
    __syncthreads();
    if (t < Nn) {
        float mv = 0.f;
#pragma unroll
        for (int j = 0; j < 8; ++j) mv += partS[t][j];
        float o = maskS[t] * disS[t] * (mv + ttS[t]) + bias0;
        alphaS[t] = 1.f / (1.f + expf(-o * o));
    }
    __syncthreads();
    if (t < Nn) {  // exact k-th largest (rank select; ties behave like sort)
        int nu = nuniq;
        if (nu > 1) {
            int idx = (int)ceilf((float)nu * 0.1f);
            if (idx > Nn - 1) idx = Nn - 1;
            float an = alphaS[t];
            int cg = 0, ce = 0;
            for (int j = 0; j < Nn; ++j) {
                float aj = alphaS[j];
                cg += (aj > an); ce += (aj == an);
            }
            if (cg <= idx && idx < cg + ce) cutS = an;  // benign same-value race
        }
    }
    __syncthreads();
    if (t < Nn) uS[t] = fmaxf(alphaS[t] + 1e-7f - cutS, 0.f) * disS[t];
    __syncthreads();
    { // matvec adj * u (row L1; all terms >= 0)
        float4 a = {0.f, 0.f, 0.f, 0.f};
#pragma unroll
        for (int j = 0; j < 4; ++j) {
            float4 v = *(float4*)&bufA[r][cbs + 4 * j];
            float4 w = *(float4*)&uS[cbs + 4 * j];
            a.x += v.x * w.x; a.y += v.y * w.y; a.z += v.z * w.z; a.w += v.w * w.w;
        }
        partS[r][seg] = (a.x + a.y) + (a.z + a.w);
    }
    __syncthreads();
    if (t < Nn) {
        float tot = uS[t];
#pragma unroll
        for (int j = 0; j < 8; ++j) tot += partS[t][j];
        float rsum = maskS[t] * disS[t] * tot;
        rowcS[t]   = maskS[t] * disS[t] / fmaxf(rsum, 1e-12f);
    }
    __syncthreads();

    // ---- build ST[m][k] = rowc_k*(adj[k][m]+delta)*u_m  (bf16, in LDS) ----
    {  // m = t&127 -> column reads 2-way free
        const int m = t & 127, sl = t >> 7, k0 = sl * 16;
        const float um = uS[m];
        float vv[16];
#pragma unroll
        for (int j = 0; j < 16; ++j) {
            int k = k0 + j;
            vv[j] = rowcS[k] * (bufA[k][m] + ((k == m) ? 1.f : 0.f)) * um;
        }
        uint4 p0, p1;
        p0.x = pk2(vv[0],  vv[1]);  p0.y = pk2(vv[2],  vv[3]);
        p0.z = pk2(vv[4],  vv[5]);  p0.w = pk2(vv[6],  vv[7]);
        p1.x = pk2(vv[8],  vv[9]);  p1.y = pk2(vv[10], vv[11]);
        p1.z = pk2(vv[12], vv[13]); p1.w = pk2(vv[14], vv[15]);
        *(uint4*)&STl[m][k0]     = p0;
        *(uint4*)&STl[m][k0 + 8] = p1;
    }
    __syncthreads();

    // ---- wave tiling: 16 waves, each owns a 16x64 C tile ----
    const int lane = t & 63, w = t >> 6;
    const int l15 = lane & 15, quad = lane >> 4;
    const int mrow  = (w & 7) * 16;
    const int nhalf = (w >> 3) * 64;
    f32x4 acc[4];

    // ---- G2: P = adj * S  (A from fp32 LDS, converted in-reg) ----
#pragma unroll
    for (int nt = 0; nt < 4; ++nt) acc[nt] = (f32x4){0.f, 0.f, 0.f, 0.f};
#pragma unroll
    for (int k0 = 0; k0 < 128; k0 += 32) {
        float av[8];
        *(float4*)&av[0] = *(float4*)&bufA[mrow + l15][k0 + quad * 8];
        *(float4*)&av[4] = *(float4*)&bufA[mrow + l15][k0 + quad * 8 + 4];
        short8 a0 = pk8(av);
#pragma unroll
        for (int nt = 0; nt < 4; ++nt) {
            short8 bf = *(const short8*)&STl[nhalf + nt * 16 + l15][k0 + quad * 8];
            acc[nt] = __builtin_amdgcn_mfma_f32_16x16x32_bf16(a0, bf, acc[nt], 0, 0, 0);
        }
    }
    __syncthreads();   // adj fp32 dead

    // ---- write P^T (bf16) into bufA region ----
    ushort (*PT)[136] = (ushort(*)[136])&bufA[0][0];
#pragma unroll
    for (int nt = 0; nt < 4; ++nt) {
        int j    = nhalf + nt * 16 + l15;
        int mcol = mrow + quad * 4;
        uint2 wv2;
        wv2.x = pk2(acc[nt][0], acc[nt][1]);
        wv2.y = pk2(acc[nt][2], acc[nt][3]);
        *(uint2*)&PT[j][mcol] = wv2;
    }
    __syncthreads();

    // ---- G3: nadj = S^T P ----
#pragma unroll
    for (int nt = 0; nt < 4; ++nt) acc[nt] = (f32x4){0.f, 0.f, 0.f, 0.f};
#pragma unroll
    for (int k0 = 0; k0 < 128; k0 += 32) {
        short8 a0 = *(const short8*)&STl[mrow + l15][k0 + quad * 8];
#pragma unroll
        for (int nt = 0; nt < 4; ++nt) {
            short8 bf = *(const short8*)&PT[nhalf + nt * 16 + l15][k0 + quad * 8];
            acc[nt] = __builtin_amdgcn_mfma_f32_16x16x32_bf16(a0, bf, acc[nt], 0, 0, 0);
        }
    }
#pragma unroll
    for (int nt = 0; nt < 4; ++nt)
#pragma unroll
        for (int rr = 0; rr < 4; ++rr) {
            int row = mrow + quad * 4 + rr;
            int col = nhalf + nt * 16 + l15;
            nadj[((size_t)b * Nn + row) * Nn + col] = acc[nt][rr];
        }
    __syncthreads();   // PT dead

    // ---- emb = S^T x, d in quarters of 64; x staged [k][d] stride 65 ----
    float (*xbufK)[65] = (float(*)[65])&bufA[0][0];   // 128*65*4 = 33280 B
    short8 aE[4];
#pragma unroll
    for (int ks = 0; ks < 4; ++ks)
        aE[ks] = *(const short8*)&STl[mrow + l15][ks * 32 + quad * 8];
    const int dcb = (w >> 3) * 32;

    for (int qd = 0; qd < 4; ++qd) {
        const int d0 = qd * 64;
#pragma unroll
        for (int i = 0; i < 2; ++i) {
            int f = t + 1024 * i;          // float4 id over 128k x 16(d4)
            int k = f >> 4, c4 = (f & 15) * 4;
            float4 v = *(const float4*)&x[((size_t)b * Nn + k) * Dd + d0 + c4];
            xbufK[k][c4]     = v.x; xbufK[k][c4 + 1] = v.y;
            xbufK[k][c4 + 2] = v.z; xbufK[k][c4 + 3] = v.w;
        }
        __syncthreads();
        f32x4 accE[2];
        accE[0] = (f32x4){0.f, 0.f, 0.f, 0.f};
        accE[1] = (f32x4){0.f, 0.f, 0.f, 0.f};
#pragma unroll
        for (int ks = 0; ks < 4; ++ks) {
#pragma unroll
            for (int s = 0; s < 2; ++s) {
                const int dcol = dcb + s * 16;
                float bv[8];
#pragma unroll
                for (int j = 0; j < 8; ++j)
                    bv[j] = xbufK[ks * 32 + quad * 8 + j][dcol + l15];
                short8 bf = pk8(bv);
                accE[s] = __builtin_amdgcn_mfma_f32_16x16x32_bf16(aE[ks], bf, accE[s], 0, 0, 0);
            }
        }
#pragma unroll
        for (int s = 0; s < 2; ++s)
#pragma unroll
            for (int rr = 0; rr < 4; ++rr) {
                int row = mrow + quad * 4 + rr;
                int col = d0 + dcb + s * 16 + l15;
                emb[((size_t)b * Nn + row) * Dd + col] = accE[s][rr];
            }
        __syncthreads();
    }
}

extern "C" void kernel_launch(void* const* d_in, const int* in_sizes, int n_in,
                              void* d_out, int out_size, void* d_ws, size_t ws_size,
                              hipStream_t stream)
{
    const float* x     = (const float*)d_in[0];
    const float* adj   = (const float*)d_in[1];
    const int*   head  = (const int*)d_in[2];
    const float* lin_w = (const float*)d_in[3];
    const float* bias  = (const float*)d_in[4];

    float* emb  = (float*)d_out;                 // [B,N,D]
    float* nadj = emb + (size_t)Bsz * Nn * Dd;   // [B,N,N]

    mega<<<Bsz, 1024, 0, stream>>>(x, adj, head, lin_w, bias, emb, nadj);
}

// Round 6
// 200.216 us; speedup vs baseline: 1.1596x; 1.0711x over previous
//
#include <hip/hip_runtime.h>

#define Bsz 512
#define Nn  128
#define Dd  256
#define Tt  512

typedef __attribute__((ext_vector_type(8))) short short8;
typedef __attribute__((ext_vector_type(4))) float f32x4;

__device__ __forceinline__ ushort f2bf(float f) {
    union { float f; unsigned u; } v; v.f = f;
    unsigned r = v.u + 0x7fffu + ((v.u >> 16) & 1u);  // RNE
    return (ushort)(r >> 16);
}
__device__ __forceinline__ unsigned pk2(float a, float b) {
    return (unsigned)f2bf(a) | ((unsigned)f2bf(b) << 16);
}
__device__ __forceinline__ float bf2f(ushort u) {
    union { unsigned u; float f; } v; v.u = (unsigned)u << 16; return v.f;
}

// One block per batch, 1024 threads, ~78 KB LDS -> 2 blocks/CU co-resident.
// Full pipeline, zero global intermediates. adj lives in LDS as bf16.
__global__ __launch_bounds__(1024, 8) void mega(
    const float* __restrict__ x, const float* __restrict__ adj,
    const int* __restrict__ head, const float* __restrict__ lin_w,
    const float* __restrict__ bias,
    float* __restrict__ emb, float* __restrict__ nadj)
{
    const int b = blockIdx.x, t = threadIdx.x;
    // adjB: adj bf16 -> P^T bf16 -> xTp (uint[128][68], bf16 k-pairs)
    __shared__ __align__(16) ushort adjB[Nn][136];   // 34816 B
    __shared__ __align__(16) ushort STl[Nn][136];    // 34816 B
    __shared__ float ttS[Nn], disS[Nn], maskS[Nn], alphaS[Nn], uS[Nn], rowcS[Nn];
    __shared__ float partS[Nn][9];                   // 4608 B, gcd(9,32)=1
    __shared__ float dotP[Nn][4];                    // 2048 B
    __shared__ int   flags[Nn];
    __shared__ int   nuniq;
    __shared__ float cutS;

    const float bias0 = bias[0];
    if (t < Nn) flags[t] = 0;
    if (t == 0) { nuniq = 0; cutS = 0.f; }

    // ---- stage adj -> bf16 LDS (read once per batch) ----
    const float* adjb = adj + (size_t)b * Nn * Nn;
#pragma unroll
    for (int i = 0; i < 4; ++i) {
        int f = t + 1024 * i;                 // float4 id
        int rr = f >> 5, c = (f & 31) * 4;
        float4 v = *(const float4*)&adjb[(size_t)rr * Nn + c];
        uint2 w2; w2.x = pk2(v.x, v.y); w2.y = pk2(v.z, v.w);
        *(uint2*)&adjB[rr][c] = w2;
    }
    __syncthreads();   // adjB + flags-init visible

    // ---- head presence ----
    if (t < Tt) { int h = head[(size_t)b * Tt + t]; flags[h] = 1; }

    // ---- lin(x) dot: 4 threads/row; w straight from global (L1 broadcast) ----
    if (t < 512) {
        const int dr = t >> 2, dh = t & 3;
        const float4* xr = (const float4*)(x + ((size_t)b * Nn + dr) * Dd + dh * 64);
        const float4* wr = (const float4*)(lin_w + dh * 64);
        float p = 0.f;
#pragma unroll
        for (int i = 0; i < 16; ++i) {
            float4 v = xr[i], w4 = wr[i];
            p += v.x * w4.x + v.y * w4.y + v.z * w4.z + v.w * w4.w;
        }
        dotP[dr][dh] = p;
    }

    // ---- row sums: 8 threads/row over bf16 adj ----
    const int r = t >> 3, seg = t & 7;
    {
        short8 a0 = *(const short8*)&adjB[r][seg * 16];
        short8 a1 = *(const short8*)&adjB[r][seg * 16 + 8];
        float s = 0.f;
#pragma unroll
        for (int j = 0; j < 8; ++j) s += bf2f((ushort)a0[j]) + bf2f((ushort)a1[j]);
        partS[r][seg] = s;
    }
    __syncthreads();

    if (t < Nn) {
        float rs = 0.f;
#pragma unroll
        for (int j = 0; j < 8; ++j) rs += partS[t][j];
        float dt = dotP[t][0] + dotP[t][1] + dotP[t][2] + dotP[t][3];
        maskS[t]  = (rs > 0.f) ? 1.f : 0.f;
        float dis = 1.f / sqrtf(fmaxf(rs + 1.f, 1.f));
        disS[t]   = dis;
        ttS[t]    = dis * dt;
        atomicAdd(&nuniq, flags[t]);
    }
    __syncthreads();

    { // matvec adj * tt
        short8 a0 = *(const short8*)&adjB[r][seg * 16];
        short8 a1 = *(const short8*)&adjB[r][seg * 16 + 8];
        float s = 0.f;
#pragma unroll
        for (int j = 0; j < 8; ++j) {
            s += bf2f((ushort)a0[j]) * ttS[seg * 16 + j];
            s += bf2f((ushort)a1[j]) * ttS[seg * 16 + 8 + j];
        }
        partS[r][seg] = s;
    }
    __syncthreads();
    if (t < Nn) {
        float mv = 0.f;
#pragma unroll
        for (int j = 0; j < 8; ++j) mv += partS[t][j];
        float o = maskS[t] * disS[t] * (mv + ttS[t]) + bias0;
        alphaS[t] = 1.f / (1.f + expf(-o * o));
    }
    __syncthreads();
    if (t < Nn) {  // exact k-th largest (rank select; ties behave like sort)
        int nu = nuniq;
        if (nu > 1) {
            int idx = (int)ceilf((float)nu * 0.1f);
            if (idx > Nn - 1) idx = Nn - 1;
            float an = alphaS[t];
            int cg = 0, ce = 0;
            for (int j = 0; j < Nn; ++j) {
                float aj = alphaS[j];
                cg += (aj > an); ce += (aj == an);
            }
            if (cg <= idx && idx < cg + ce) cutS = an;  // benign same-value race
        }
    }
    __syncthreads();
    if (t < Nn) uS[t] = fmaxf(alphaS[t] + 1e-7f - cutS, 0.f) * disS[t];
    __syncthreads();
    { // matvec adj * u (row L1; all terms >= 0)
        short8 a0 = *(const short8*)&adjB[r][seg * 16];
        short8 a1 = *(const short8*)&adjB[r][seg * 16 + 8];
        float s = 0.f;
#pragma unroll
        for (int j = 0; j < 8; ++j) {
            s += bf2f((ushort)a0[j]) * uS[seg * 16 + j];
            s += bf2f((ushort)a1[j]) * uS[seg * 16 + 8 + j];
        }
        partS[r][seg] = s;
    }
    __syncthreads();
    if (t < Nn) {
        float tot = uS[t];
#pragma unroll
        for (int j = 0; j < 8; ++j) tot += partS[t][j];
        float rsum = maskS[t] * disS[t] * tot;
        rowcS[t]   = maskS[t] * disS[t] / fmaxf(rsum, 1e-12f);
    }
    __syncthreads();

    // ---- build ST[m][k] = rowc_k*(adj[k][m]+delta)*u_m  (bf16, in LDS) ----
    {
        const int m = t & 127, sl = t >> 7, k0 = sl * 16;
        const float um = uS[m];
        float vv[16];
#pragma unroll
        for (int j = 0; j < 16; ++j) {
            int k = k0 + j;
            vv[j] = rowcS[k] * (bf2f(adjB[k][m]) + ((k == m) ? 1.f : 0.f)) * um;
        }
        uint4 p0, p1;
        p0.x = pk2(vv[0],  vv[1]);  p0.y = pk2(vv[2],  vv[3]);
        p0.z = pk2(vv[4],  vv[5]);  p0.w = pk2(vv[6],  vv[7]);
        p1.x = pk2(vv[8],  vv[9]);  p1.y = pk2(vv[10], vv[11]);
        p1.z = pk2(vv[12], vv[13]); p1.w = pk2(vv[14], vv[15]);
        *(uint4*)&STl[m][k0]     = p0;
        *(uint4*)&STl[m][k0 + 8] = p1;
    }
    __syncthreads();

    // ---- wave tiling: 16 waves, each a 16x64 C tile ----
    const int lane = t & 63, w = t >> 6;
    const int l15 = lane & 15, quad = lane >> 4;
    const int mrow  = (w & 7) * 16;
    const int nhalf = (w >> 3) * 64;
    f32x4 acc[4];

    // ---- G2: P = adj * S ----
#pragma unroll
    for (int nt = 0; nt < 4; ++nt) acc[nt] = (f32x4){0.f, 0.f, 0.f, 0.f};
#pragma unroll
    for (int k0 = 0; k0 < 128; k0 += 32) {
        short8 a0 = *(const short8*)&adjB[mrow + l15][k0 + quad * 8];
#pragma unroll
        for (int nt = 0; nt < 4; ++nt) {
            short8 bf = *(const short8*)&STl[nhalf + nt * 16 + l15][k0 + quad * 8];
            acc[nt] = __builtin_amdgcn_mfma_f32_16x16x32_bf16(a0, bf, acc[nt], 0, 0, 0);
        }
    }
    __syncthreads();   // adj bf16 dead

    // ---- write P^T (bf16) into adjB region ----
    ushort (*PT)[136] = (ushort(*)[136])&adjB[0][0];
#pragma unroll
    for (int nt = 0; nt < 4; ++nt) {
        int j    = nhalf + nt * 16 + l15;
        int mcol = mrow + quad * 4;
        uint2 w2;
        w2.x = pk2(acc[nt][0], acc[nt][1]);
        w2.y = pk2(acc[nt][2], acc[nt][3]);
        *(uint2*)&PT[j][mcol] = w2;
    }
    __syncthreads();

    // ---- G3: nadj = S^T P ----
#pragma unroll
    for (int nt = 0; nt < 4; ++nt) acc[nt] = (f32x4){0.f, 0.f, 0.f, 0.f};
#pragma unroll
    for (int k0 = 0; k0 < 128; k0 += 32) {
        short8 a0 = *(const short8*)&STl[mrow + l15][k0 + quad * 8];
#pragma unroll
        for (int nt = 0; nt < 4; ++nt) {
            short8 bf = *(const short8*)&PT[nhalf + nt * 16 + l15][k0 + quad * 8];
            acc[nt] = __builtin_amdgcn_mfma_f32_16x16x32_bf16(a0, bf, acc[nt], 0, 0, 0);
        }
    }
#pragma unroll
    for (int nt = 0; nt < 4; ++nt)
#pragma unroll
        for (int rr = 0; rr < 4; ++rr) {
            int row = mrow + quad * 4 + rr;
            int col = nhalf + nt * 16 + l15;
            nadj[((size_t)b * Nn + row) * Nn + col] = acc[nt][rr];
        }
    __syncthreads();   // PT dead

    // ---- emb = S^T x; x staged as bf16 k-pairs xTp[d][kp] in dead region ----
    uint (*xTp)[68] = (uint(*)[68])&adjB[0][0];      // 128*68*4 = 34816 B
    short8 aE[4];
#pragma unroll
    for (int ks = 0; ks < 4; ++ks)
        aE[ks] = *(const short8*)&STl[mrow + l15][ks * 32 + quad * 8];
    const int dcb = (w >> 3) * 64;

    for (int half = 0; half < 2; ++half) {
        const int d0 = half * 128;
#pragma unroll
        for (int i = 0; i < 2; ++i) {
            int f = t + 1024 * i;              // d4 = f&31 (x4 d), kp = f>>5
            int d4 = f & 31, kp = f >> 5;
            const float* xp = x + ((size_t)b * Nn + 2 * kp) * Dd + d0 + 4 * d4;
            float4 ve = *(const float4*)xp;
            float4 vo = *(const float4*)(xp + Dd);
            xTp[4 * d4    ][kp] = pk2(ve.x, vo.x);
            xTp[4 * d4 + 1][kp] = pk2(ve.y, vo.y);
            xTp[4 * d4 + 2][kp] = pk2(ve.z, vo.z);
            xTp[4 * d4 + 3][kp] = pk2(ve.w, vo.w);
        }
        __syncthreads();
        f32x4 accE[4];
#pragma unroll
        for (int nt = 0; nt < 4; ++nt) accE[nt] = (f32x4){0.f, 0.f, 0.f, 0.f};
#pragma unroll
        for (int ks = 0; ks < 4; ++ks) {
#pragma unroll
            for (int nt = 0; nt < 4; ++nt) {
                short8 bf = *(const short8*)&xTp[dcb + nt * 16 + l15][ks * 16 + quad * 4];
                accE[nt] = __builtin_amdgcn_mfma_f32_16x16x32_bf16(aE[ks], bf, accE[nt], 0, 0, 0);
            }
        }
#pragma unroll
        for (int nt = 0; nt < 4; ++nt)
#pragma unroll
            for (int rr = 0; rr < 4; ++rr) {
                int row = mrow + quad * 4 + rr;
                int col = d0 + dcb + nt * 16 + l15;
                emb[((size_t)b * Nn + row) * Dd + col] = accE[nt][rr];
            }
        __syncthreads();
    }
}

extern "C" void kernel_launch(void* const* d_in, const int* in_sizes, int n_in,
                              void* d_out, int out_size, void* d_ws, size_t ws_size,
                              hipStream_t stream)
{
    const float* x     = (const float*)d_in[0];
    const float* adj   = (const float*)d_in[1];
    const int*   head  = (const int*)d_in[2];
    const float* lin_w = (const float*)d_in[3];
    const float* bias  = (const float*)d_in[4];

    float* emb  = (float*)d_out;                 // [B,N,D]
    float* nadj = emb + (size_t)Bsz * Nn * Dd;   // [B,N,N]

    mega<<<Bsz, 1024, 0, stream>>>(x, adj, head, lin_w, bias, emb, nadj);
}